// Round 1
// baseline (229.350 us; speedup 1.0000x reference)
//
#include <hip/hip_runtime.h>

#define NOUT 50000
#define KNB 32            // neighbors per output point
#define CIN 16
#define COUT 32
#define NTAP 64
#define GP 16             // points per block (= waves per block)
#define ROWB 2064         // bytes per point row in s_bl: 1024 bf16 (2048B) + 16B pad
#define ROWU (ROWB / 4)   // 516 u32 per row

typedef __attribute__((ext_vector_type(8))) short short8;
typedef __attribute__((ext_vector_type(4))) float f32x4;

__device__ __forceinline__ unsigned int f2bf(float f) {
  // fp32 -> bf16 bits, round-to-nearest-even
  unsigned int u = __float_as_uint(f);
  return (u + 0x7fffu + ((u >> 16) & 1u)) >> 16;
}

// ---- prep: convert kernel [64][16][32] f32 -> frag-ordered bf16 ----
// Wf[s][g][n][j] = bf16(W[kc = s*32 + g*8 + j][n]);  s=kstep(32), g=lane>>4 group(4),
// n=cout(32), j=0..7 -> each MFMA B-fragment lane load is one contiguous 16B read.
__global__ void prep_w_kernel(const float* __restrict__ kern,
                              unsigned short* __restrict__ wf) {
  int idx = blockIdx.x * 256 + threadIdx.x;
  if (idx >= NTAP * CIN * COUT) return;  // 32768
  int j = idx & 7;
  int n = (idx >> 3) & 31;
  int g = (idx >> 8) & 3;
  int s = idx >> 10;
  int kc = s * 32 + g * 8 + j;
  wf[idx] = (unsigned short)f2bf(kern[kc * COUT + n]);
}

__launch_bounds__(1024)
__global__ void cconv_kernel(const float* __restrict__ feats,
                             const float* __restrict__ inp_points,
                             const float* __restrict__ out_points,
                             const float* __restrict__ out_extents,
                             const float* __restrict__ scale_compat,
                             const int* __restrict__ nidx,
                             const float* __restrict__ ndist,
                             const unsigned short* __restrict__ wf,
                             const float* __restrict__ bias,
                             float* __restrict__ out) {
  // per-point bf16 tap accumulator B[p][kc=tap*16+c], +16B pad/row for bank spread
  __shared__ __align__(16) unsigned int s_bl[GP * ROWU];       // 33024 B
  __shared__ unsigned int s_wk[GP][KNB][8];                    // 16384 B: (bf16 w)<<16 | k
  __shared__ float s_cacc[GP][COUT];                           // 2048 B
  __shared__ float s_den[GP];

  const int tid = threadIdx.x;
  const int wv = tid >> 6;     // wave id = point within block
  const int lane = tid & 63;
  const int pg = blockIdx.x * GP + wv;   // global output point

  // zero accumulators
  for (int i = tid; i < GP * ROWU; i += 1024) s_bl[i] = 0u;
  if (tid < GP * COUT) ((float*)s_cacc)[tid] = 0.0f;

  // ---- phase 1: geometry, lanes 0..31 each own one edge ----
  float imp = 0.0f;
  if (lane < KNB) {
    const int eg = pg * KNB + lane;
    const int nb = nidx[eg];
    const float d = ndist[eg];
    float q = 1.0f - d * d;
    float w6 = q * q * q;
    w6 = fminf(fmaxf(w6, 0.0f), 1.0f);
    imp = scale_compat[eg] * w6;

    const float inv = 1.0f / (0.5f * out_extents[pg]);
    const float rx = (inp_points[nb * 3 + 0] - out_points[pg * 3 + 0]) * inv;
    const float ry = (inp_points[nb * 3 + 1] - out_points[pg * 3 + 1]) * inv;
    const float rz = (inp_points[nb * 3 + 2] - out_points[pg * 3 + 2]) * inv;
    const float r = sqrtf(rx * rx + ry * ry + rz * rz);
    const float linf = fmaxf(fabsf(rx), fmaxf(fabsf(ry), fabsf(rz)));
    const float sf = r / fmaxf(linf, 1e-12f);
    const float ux = rx * sf, uy = ry * sf, uz = rz * sf;

    const float tx = fminf(fmaxf((ux * 0.5f + 0.5f) * 3.0f, 0.0f), 3.0f);
    const float ty = fminf(fmaxf((uy * 0.5f + 0.5f) * 3.0f, 0.0f), 3.0f);
    const float tz = fminf(fmaxf((uz * 0.5f + 0.5f) * 3.0f, 0.0f), 3.0f);
    const float t0x = fminf(floorf(tx), 2.0f);
    const float t0y = fminf(floorf(ty), 2.0f);
    const float t0z = fminf(floorf(tz), 2.0f);
    const float fx = tx - t0x, fy = ty - t0y, fz = tz - t0z;
    const int ix = (int)t0x, iy = (int)t0y, iz = (int)t0z;

    const float wx[2] = {1.0f - fx, fx};
    const float wy[2] = {1.0f - fy, fy};
    const float wz[2] = {1.0f - fz, fz};
#pragma unroll
    for (int dx = 0; dx < 2; ++dx)
#pragma unroll
      for (int dy = 0; dy < 2; ++dy)
#pragma unroll
        for (int dz = 0; dz < 2; ++dz) {
          const int t = dx * 4 + dy * 2 + dz;
          const float w = wx[dx] * wy[dy] * wz[dz] * imp;  // fold imp into tap weight
          const int k = ((ix + dx) * 4 + (iy + dy)) * 4 + (iz + dz);
          s_wk[wv][lane][t] = (f2bf(w) << 16) | (unsigned int)k;
        }
  }
  // den = sum(imp) over the wave (lanes >=32 contribute 0)
  float dsum = imp;
#pragma unroll
  for (int m = 1; m < 64; m <<= 1) dsum += __shfl_xor(dsum, m);
  if (lane == 0) s_den[wv] = dsum;

  __syncthreads();

  // ---- phase 2: scatter. 64 lanes = 8 taps x 8 channel-pairs, bf16x2 RMW.
  // The 8 trilinear taps of one edge are distinct cells -> distinct addresses
  // within each iteration -> lockstep wave RMW is race-free without atomics.
  {
    const int t = lane >> 3;
    const int cp = lane & 7;
    const unsigned int rowu = (unsigned int)(wv * ROWU);
    for (int e = 0; e < KNB; ++e) {
      const unsigned int wk = s_wk[wv][e][t];
      const int k = (int)(wk & 63u);
      const float w = __uint_as_float(wk & 0xffff0000u);   // bf16 w in high bits
      const int nb = nidx[pg * KNB + e];                    // wave-uniform broadcast
      const float2 f2 = *(const float2*)(feats + nb * CIN + cp * 2);
      // byte offset of kc = k*16 + cp*2 (bf16), with k-bit XOR swizzle to break
      // the (k mod 4) 4-way bank conflict; same swizzle applied on A-frag read.
      unsigned int byte = ((unsigned int)k << 5) | ((unsigned int)cp << 2);
      byte ^= (((unsigned int)k >> 2) & 7u) << 4;
      const unsigned int ui = rowu + (byte >> 2);
      const unsigned int old = s_bl[ui];
      float lo = __uint_as_float(old << 16);
      float hi = __uint_as_float(old & 0xffff0000u);
      lo = fmaf(w, f2.x, lo);
      hi = fmaf(w, f2.y, hi);
      s_bl[ui] = (f2bf(hi) << 16) | f2bf(lo);
    }
  }

  __syncthreads();

  // ---- phase 3: MFMA contraction. M-tile = 16 points, N = 32 (two 16-col frags),
  // K = 1024 split across 16 waves (2 ksteps of 32 each). ----
  f32x4 acc0 = {0.f, 0.f, 0.f, 0.f}, acc1 = {0.f, 0.f, 0.f, 0.f};
  const int pl = lane & 15;   // A row = point, B col = cout
  const int g4 = lane >> 4;   // k-group
#pragma unroll
  for (int ss = 0; ss < 2; ++ss) {
    const int s = wv * 2 + ss;
    unsigned int byte = (unsigned int)(s * 64 + g4 * 16);   // = kc0 * 2
    const int tap = (int)(byte >> 5);
    byte ^= (((unsigned int)tap >> 2) & 7u) << 4;           // same swizzle as scatter
    const short8 a = *(const short8*)((const char*)s_bl + pl * ROWB + byte);
    const short8 b0 = *(const short8*)(wf + ((unsigned)((s * 4 + g4) * 32) + pl) * 8);
    const short8 b1 = *(const short8*)(wf + ((unsigned)((s * 4 + g4) * 32) + 16 + pl) * 8);
    acc0 = __builtin_amdgcn_mfma_f32_16x16x32_bf16(a, b0, acc0, 0, 0, 0);
    acc1 = __builtin_amdgcn_mfma_f32_16x16x32_bf16(a, b1, acc1, 0, 0, 0);
  }
  // cross-wave K-reduction: D row = (lane>>4)*4 + j = point, col = lane&15 = cout
#pragma unroll
  for (int j = 0; j < 4; ++j) {
    const int row = g4 * 4 + j;
    atomicAdd(&s_cacc[row][pl], acc0[j]);
    atomicAdd(&s_cacc[row][pl + 16], acc1[j]);
  }

  __syncthreads();

  // ---- epilogue: normalize, bias, relu ----
  if (tid < GP * COUT) {
    const int p = tid >> 5;
    const int d = tid & 31;
    const float den = s_den[p];
    float v = ((float*)s_cacc)[tid] / (den > 0.0f ? den : 1.0f) + bias[d];
    out[blockIdx.x * (GP * COUT) + tid] = fmaxf(v, 0.0f);
  }
}

extern "C" void kernel_launch(void* const* d_in, const int* in_sizes, int n_in,
                              void* d_out, int out_size, void* d_ws, size_t ws_size,
                              hipStream_t stream) {
  const float* feats        = (const float*)d_in[0];
  const float* inp_points   = (const float*)d_in[1];
  const float* out_points   = (const float*)d_in[2];
  const float* out_extents  = (const float*)d_in[3];
  const float* scale_compat = (const float*)d_in[4];
  const int*   nidx         = (const int*)d_in[5];
  // d_in[6] = neighbors_row_splits: fixed arange*K structure, not needed
  const float* ndist        = (const float*)d_in[7];
  const float* kern         = (const float*)d_in[8];
  const float* bias         = (const float*)d_in[9];
  unsigned short* wf = (unsigned short*)d_ws;  // 64 KiB frag-ordered bf16 kernel

  prep_w_kernel<<<(NTAP * CIN * COUT + 255) / 256, 256, 0, stream>>>(kern, wf);
  cconv_kernel<<<NOUT / GP, 1024, 0, stream>>>(feats, inp_points, out_points,
                                               out_extents, scale_compat, nidx,
                                               ndist, wf, bias, (float*)d_out);
}

// Round 2
// 186.652 us; speedup vs baseline: 1.2288x; 1.2288x over previous
//
#include <hip/hip_runtime.h>
#include <hip/hip_bf16.h>

#define NOUT 50000
#define KNB 32            // neighbors per output point
#define CIN 16
#define COUT 32
#define NTAP 64
#define GP 16             // points per block (= waves per block)
#define ROWB 2064         // bytes per point row in s_bl: 1024 bf16 (2048B) + 16B pad
#define ROWU (ROWB / 4)   // 516 u32 per row

typedef __attribute__((ext_vector_type(8))) short short8;
typedef __attribute__((ext_vector_type(4))) float f32x4;

__device__ __forceinline__ unsigned int pk2(float lo, float hi) {
  // pack two f32 -> bf16x2 (RNE), lo -> bits[15:0]
  union { __hip_bfloat162 h2; unsigned int u; } cv;
  cv.h2 = __float22bfloat162_rn(make_float2(lo, hi));
  return cv.u;
}

__device__ __forceinline__ unsigned int f2bf(float f) {
  unsigned int u = __float_as_uint(f);
  return (u + 0x7fffu + ((u >> 16) & 1u)) >> 16;
}

// ---- prep: convert kernel [64][16][32] f32 -> frag-ordered bf16 ----
// Wf[s][g][n][j] = bf16(W[kc = s*32 + g*8 + j][n])
__global__ void prep_w_kernel(const float* __restrict__ kern,
                              unsigned short* __restrict__ wf) {
  int idx = blockIdx.x * 256 + threadIdx.x;
  if (idx >= NTAP * CIN * COUT) return;  // 32768
  int j = idx & 7;
  int n = (idx >> 3) & 31;
  int g = (idx >> 8) & 3;
  int s = idx >> 10;
  int kc = s * 32 + g * 8 + j;
  wf[idx] = (unsigned short)f2bf(kern[kc * COUT + n]);
}

__launch_bounds__(1024)
__global__ void cconv_kernel(const float* __restrict__ feats,
                             const float* __restrict__ inp_points,
                             const float* __restrict__ out_points,
                             const float* __restrict__ out_extents,
                             const float* __restrict__ scale_compat,
                             const int* __restrict__ nidx,
                             const float* __restrict__ ndist,
                             const unsigned short* __restrict__ wf,
                             const float* __restrict__ bias,
                             float* __restrict__ out) {
  __shared__ __align__(16) unsigned int s_bl[GP * ROWU];   // 33024 B bf16 B-accum
  __shared__ float4 s_ed[GP * KNB];                        // 8192 B (tx,ty,tz,imp)
  __shared__ int s_nb[GP * KNB];                           // 2048 B neighbor ids
  __shared__ float s_cacc[GP][COUT];                       // 2048 B
  __shared__ float s_den[GP];

  const int tid = threadIdx.x;
  const int wv = tid >> 6;     // wave id = point within block
  const int lane = tid & 63;
  const int pg = blockIdx.x * GP + wv;   // global output point

  if (tid < GP * COUT) ((float*)s_cacc)[tid] = 0.0f;

  // ---- phase 1: geometry, lanes 0..31 each own one edge ----
  float imp = 0.0f;
  if (lane < KNB) {
    const int eg = pg * KNB + lane;
    const int nb = nidx[eg];
    const float d = ndist[eg];
    float q = 1.0f - d * d;
    float w6 = q * q * q;
    w6 = fminf(fmaxf(w6, 0.0f), 1.0f);
    imp = scale_compat[eg] * w6;

    const float inv = 1.0f / (0.5f * out_extents[pg]);
    const float rx = (inp_points[nb * 3 + 0] - out_points[pg * 3 + 0]) * inv;
    const float ry = (inp_points[nb * 3 + 1] - out_points[pg * 3 + 1]) * inv;
    const float rz = (inp_points[nb * 3 + 2] - out_points[pg * 3 + 2]) * inv;
    const float r = sqrtf(rx * rx + ry * ry + rz * rz);
    const float linf = fmaxf(fabsf(rx), fmaxf(fabsf(ry), fabsf(rz)));
    const float sf = r / fmaxf(linf, 1e-12f);
    const float tx = fminf(fmaxf((rx * sf * 0.5f + 0.5f) * 3.0f, 0.0f), 3.0f);
    const float ty = fminf(fmaxf((ry * sf * 0.5f + 0.5f) * 3.0f, 0.0f), 3.0f);
    const float tz = fminf(fmaxf((rz * sf * 0.5f + 0.5f) * 3.0f, 0.0f), 3.0f);

    s_ed[wv * KNB + lane] = make_float4(tx, ty, tz, imp);
    s_nb[wv * KNB + lane] = nb;
  }
  // den = sum(imp) over the wave
  float dsum = imp;
#pragma unroll
  for (int m = 1; m < 64; m <<= 1) dsum += __shfl_xor(dsum, m);
  if (lane == 0) s_den[wv] = dsum;

  __syncthreads();

  // ---- phase 2: per-point GEMM1 via MFMA: B(64x16) = W(64x32) * Fe(32x16).
  // Hat weights: w[k,e] = hx(kx)*hy(ky)*hz(kz)*imp_e, h(m)=max(0,1-|t-m|),
  // identical to the reference trilinear weights (incl. floor/clip edges).
  {
    const int c = lane & 15;     // = B-frag col (chan) AND A-frag row (tap-in-tile)
    const int g = lane >> 4;     // k-group: edges 8g..8g+7
    const float kyf = (float)(c >> 2);
    const float kzf = (float)(c & 3);
    union { unsigned int u[4]; short8 v; } wfr0, wfr1, wfr2, wfr3, fef;
    float wprev0, wprev1, wprev2, wprev3, feprev;
#pragma unroll
    for (int j = 0; j < 8; ++j) {
      const float4 ed = s_ed[wv * KNB + g * 8 + j];
      const int nb = s_nb[wv * KNB + g * 8 + j];
      const float f = feats[nb * CIN + c];
      const float hy = fmaxf(0.0f, 1.0f - fabsf(ed.y - kyf));
      const float hz = fmaxf(0.0f, 1.0f - fabsf(ed.z - kzf));
      const float m = hy * hz * ed.w;   // fold imp into W
      const float w0 = fmaxf(0.0f, 1.0f - fabsf(ed.x - 0.0f)) * m;
      const float w1 = fmaxf(0.0f, 1.0f - fabsf(ed.x - 1.0f)) * m;
      const float w2 = fmaxf(0.0f, 1.0f - fabsf(ed.x - 2.0f)) * m;
      const float w3 = fmaxf(0.0f, 1.0f - fabsf(ed.x - 3.0f)) * m;
      if (j & 1) {
        wfr0.u[j >> 1] = pk2(wprev0, w0);
        wfr1.u[j >> 1] = pk2(wprev1, w1);
        wfr2.u[j >> 1] = pk2(wprev2, w2);
        wfr3.u[j >> 1] = pk2(wprev3, w3);
        fef.u[j >> 1] = pk2(feprev, f);
      } else {
        wprev0 = w0; wprev1 = w1; wprev2 = w2; wprev3 = w3; feprev = f;
      }
    }
    const f32x4 z = {0.f, 0.f, 0.f, 0.f};
    f32x4 d1[4];
    d1[0] = __builtin_amdgcn_mfma_f32_16x16x32_bf16(wfr0.v, fef.v, z, 0, 0, 0);
    d1[1] = __builtin_amdgcn_mfma_f32_16x16x32_bf16(wfr1.v, fef.v, z, 0, 0, 0);
    d1[2] = __builtin_amdgcn_mfma_f32_16x16x32_bf16(wfr2.v, fef.v, z, 0, 0, 0);
    d1[3] = __builtin_amdgcn_mfma_f32_16x16x32_bf16(wfr3.v, fef.v, z, 0, 0, 0);

    // D1: row = tap-in-tile = g*4+jj, col = chan = lane&15. Pack chan pairs
    // via shfl_xor(1) (lane^1 <=> c^1), even-c lanes write bf16x2, XOR-swizzled
    // identically to the phase-3 A-frag read.
#pragma unroll
    for (int tile = 0; tile < 4; ++tile) {
#pragma unroll
      for (int jj = 0; jj < 4; ++jj) {
        const float v = d1[tile][jj];
        const float vn = __shfl_xor(v, 1);
        const unsigned int pk = pk2(v, vn);
        const int t = tile * 16 + g * 4 + jj;
        unsigned int byte = (unsigned int)(t * 32 + (c & ~1) * 2);
        byte ^= ((unsigned int)(t >> 2) & 7u) << 4;
        if (!(lane & 1))
          *(unsigned int*)((char*)s_bl + wv * ROWB + byte) = pk;
      }
    }
  }

  __syncthreads();

  // ---- phase 3: GEMM2. M = 16 points, N = 32, K = 1024 split over 16 waves ----
  f32x4 acc0 = {0.f, 0.f, 0.f, 0.f}, acc1 = {0.f, 0.f, 0.f, 0.f};
  const int pl = lane & 15;
  const int g4 = lane >> 4;
#pragma unroll
  for (int ss = 0; ss < 2; ++ss) {
    const int s = wv * 2 + ss;
    unsigned int byte = (unsigned int)(s * 64 + g4 * 16);
    const int tap = (int)(byte >> 5);
    byte ^= (((unsigned int)tap >> 2) & 7u) << 4;
    const short8 a = *(const short8*)((const char*)s_bl + pl * ROWB + byte);
    const short8 b0 = *(const short8*)(wf + ((unsigned)((s * 4 + g4) * 32) + pl) * 8);
    const short8 b1 = *(const short8*)(wf + ((unsigned)((s * 4 + g4) * 32) + 16 + pl) * 8);
    acc0 = __builtin_amdgcn_mfma_f32_16x16x32_bf16(a, b0, acc0, 0, 0, 0);
    acc1 = __builtin_amdgcn_mfma_f32_16x16x32_bf16(a, b1, acc1, 0, 0, 0);
  }
#pragma unroll
  for (int j = 0; j < 4; ++j) {
    const int row = g4 * 4 + j;
    atomicAdd(&s_cacc[row][pl], acc0[j]);
    atomicAdd(&s_cacc[row][pl + 16], acc1[j]);
  }

  __syncthreads();

  // ---- epilogue: normalize, bias, relu ----
  if (tid < GP * COUT) {
    const int p = tid >> 5;
    const int d = tid & 31;
    const float den = s_den[p];
    float v = ((float*)s_cacc)[tid] / (den > 0.0f ? den : 1.0f) + bias[d];
    out[blockIdx.x * (GP * COUT) + tid] = fmaxf(v, 0.0f);
  }
}

extern "C" void kernel_launch(void* const* d_in, const int* in_sizes, int n_in,
                              void* d_out, int out_size, void* d_ws, size_t ws_size,
                              hipStream_t stream) {
  const float* feats        = (const float*)d_in[0];
  const float* inp_points   = (const float*)d_in[1];
  const float* out_points   = (const float*)d_in[2];
  const float* out_extents  = (const float*)d_in[3];
  const float* scale_compat = (const float*)d_in[4];
  const int*   nidx         = (const int*)d_in[5];
  const float* ndist        = (const float*)d_in[7];
  const float* kern         = (const float*)d_in[8];
  const float* bias         = (const float*)d_in[9];
  unsigned short* wf = (unsigned short*)d_ws;  // 64 KiB frag-ordered bf16 kernel

  prep_w_kernel<<<(NTAP * CIN * COUT + 255) / 256, 256, 0, stream>>>(kern, wf);
  cconv_kernel<<<NOUT / GP, 1024, 0, stream>>>(feats, inp_points, out_points,
                                               out_extents, scale_compat, nidx,
                                               ndist, wf, bias, (float*)d_out);
}

// Round 3
// 107.926 us; speedup vs baseline: 2.1251x; 1.7294x over previous
//
#include <hip/hip_runtime.h>
#include <hip/hip_bf16.h>

#define NOUT 50000
#define KNB 32            // neighbors per output point
#define CIN 16
#define COUT 32
#define NTAP 64
#define GP 8              // points per block (= waves per block)
#define ROWB 4112         // bytes per point row in s_bl: 64*16*4 + 16 pad
                          // (stride/4 = 1028 == 4 mod 32 -> spreads phase-3 row reads)

typedef __attribute__((ext_vector_type(8))) short short8;
typedef __attribute__((ext_vector_type(4))) float f32x4;

__device__ __forceinline__ unsigned int pk2(float lo, float hi) {
  union { __hip_bfloat162 h2; unsigned int u; } cv;
  cv.h2 = __float22bfloat162_rn(make_float2(lo, hi));
  return cv.u;
}

__device__ __forceinline__ unsigned int f2bf(float f) {
  unsigned int u = __float_as_uint(f);
  return (u + 0x7fffu + ((u >> 16) & 1u)) >> 16;
}

// Wf[s][g][n][j] = bf16(W[kc = s*32 + g*8 + j][n])
__global__ void prep_w_kernel(const float* __restrict__ kern,
                              unsigned short* __restrict__ wf) {
  int idx = blockIdx.x * 256 + threadIdx.x;
  if (idx >= NTAP * CIN * COUT) return;  // 32768
  int j = idx & 7;
  int n = (idx >> 3) & 31;
  int g = (idx >> 8) & 3;
  int s = idx >> 10;
  int kc = s * 32 + g * 8 + j;
  wf[idx] = (unsigned short)f2bf(kern[kc * COUT + n]);
}

__launch_bounds__(512)
__global__ void cconv_kernel(const float* __restrict__ feats,
                             const float* __restrict__ inp_points,
                             const float* __restrict__ out_points,
                             const float* __restrict__ out_extents,
                             const float* __restrict__ scale_compat,
                             const int* __restrict__ nidx,
                             const float* __restrict__ ndist,
                             const unsigned short* __restrict__ wf,
                             const float* __restrict__ bias,
                             float* __restrict__ out) {
  // f32 B accumulator; element (t,c) of point p at byte:
  //   p*ROWB + (t>>1)*128 + (((t&1)^((t>>2)&1))<<6) + c*4
  __shared__ __align__(16) char s_bl[GP * ROWB];           // 32896 B
  __shared__ float4 s_ed[GP * KNB];                        // 4096 B (tx,ty,tz,imp)
  __shared__ int s_nb[GP * KNB];                           // 1024 B
  __shared__ float s_cacc[GP][COUT];                       // 1024 B
  __shared__ float s_den[GP];

  const int tid = threadIdx.x;
  const int wv = tid >> 6;
  const int lane = tid & 63;
  const int pg = blockIdx.x * GP + wv;

  if (tid < GP * COUT) ((float*)s_cacc)[tid] = 0.0f;

  // ---- phase 1: geometry, lanes 0..31 each own one edge ----
  float imp = 0.0f;
  if (lane < KNB) {
    const int eg = pg * KNB + lane;
    const int nb = nidx[eg];
    const float d = ndist[eg];
    float q = 1.0f - d * d;
    float w6 = q * q * q;
    w6 = fminf(fmaxf(w6, 0.0f), 1.0f);
    imp = scale_compat[eg] * w6;

    const float inv = 1.0f / (0.5f * out_extents[pg]);
    const float rx = (inp_points[nb * 3 + 0] - out_points[pg * 3 + 0]) * inv;
    const float ry = (inp_points[nb * 3 + 1] - out_points[pg * 3 + 1]) * inv;
    const float rz = (inp_points[nb * 3 + 2] - out_points[pg * 3 + 2]) * inv;
    const float r = sqrtf(rx * rx + ry * ry + rz * rz);
    const float linf = fmaxf(fabsf(rx), fmaxf(fabsf(ry), fabsf(rz)));
    const float sf = r / fmaxf(linf, 1e-12f);
    const float tx = fminf(fmaxf((rx * sf * 0.5f + 0.5f) * 3.0f, 0.0f), 3.0f);
    const float ty = fminf(fmaxf((ry * sf * 0.5f + 0.5f) * 3.0f, 0.0f), 3.0f);
    const float tz = fminf(fmaxf((rz * sf * 0.5f + 0.5f) * 3.0f, 0.0f), 3.0f);

    s_ed[wv * KNB + lane] = make_float4(tx, ty, tz, imp);
    s_nb[wv * KNB + lane] = nb;
  }
  float dsum = imp;
#pragma unroll
  for (int m = 1; m < 64; m <<= 1) dsum += __shfl_xor(dsum, m);
  if (lane == 0) s_den[wv] = dsum;

  __syncthreads();

  // ---- phase 2: per-point GEMM1: B(64x16) = W(64x32) * Fe(32x16) ----
  {
    const int c = lane & 15;
    const int g = lane >> 4;
    const float kyf = (float)(c >> 2);
    const float kzf = (float)(c & 3);
    union { unsigned int u[4]; short8 v; } wfr0, wfr1, wfr2, wfr3, fef;
    float wprev0, wprev1, wprev2, wprev3, feprev;
#pragma unroll
    for (int j = 0; j < 8; ++j) {
      const float4 ed = s_ed[wv * KNB + g * 8 + j];
      const int nb = s_nb[wv * KNB + g * 8 + j];
      const float f = feats[nb * CIN + c];
      const float hy = fmaxf(0.0f, 1.0f - fabsf(ed.y - kyf));
      const float hz = fmaxf(0.0f, 1.0f - fabsf(ed.z - kzf));
      const float m = hy * hz * ed.w;
      const float w0 = fmaxf(0.0f, 1.0f - ed.x) * m;
      const float w1 = fmaxf(0.0f, 1.0f - fabsf(ed.x - 1.0f)) * m;
      const float w2 = fmaxf(0.0f, 1.0f - fabsf(ed.x - 2.0f)) * m;
      const float w3 = fmaxf(0.0f, ed.x - 2.0f) * m;
      if (j & 1) {
        wfr0.u[j >> 1] = pk2(wprev0, w0);
        wfr1.u[j >> 1] = pk2(wprev1, w1);
        wfr2.u[j >> 1] = pk2(wprev2, w2);
        wfr3.u[j >> 1] = pk2(wprev3, w3);
        fef.u[j >> 1] = pk2(feprev, f);
      } else {
        wprev0 = w0; wprev1 = w1; wprev2 = w2; wprev3 = w3; feprev = f;
      }
    }
    const f32x4 z = {0.f, 0.f, 0.f, 0.f};
    f32x4 d1[4];
    d1[0] = __builtin_amdgcn_mfma_f32_16x16x32_bf16(wfr0.v, fef.v, z, 0, 0, 0);
    d1[1] = __builtin_amdgcn_mfma_f32_16x16x32_bf16(wfr1.v, fef.v, z, 0, 0, 0);
    d1[2] = __builtin_amdgcn_mfma_f32_16x16x32_bf16(wfr2.v, fef.v, z, 0, 0, 0);
    d1[3] = __builtin_amdgcn_mfma_f32_16x16x32_bf16(wfr3.v, fef.v, z, 0, 0, 0);

    const unsigned int pbE = (unsigned)(wv * ROWB + g * 256 + ((g & 1) << 6) + c * 4);
    const unsigned int pbO = (unsigned)(wv * ROWB + g * 256 + (((g & 1) ^ 1) << 6) + c * 4);
#pragma unroll
    for (int tile = 0; tile < 4; ++tile) {
#pragma unroll
      for (int jj = 0; jj < 4; ++jj) {
        const unsigned int addr = ((jj & 1) ? pbO : pbE)
                                + (unsigned)(tile * 1024 + (jj >> 1) * 128);
        *(float*)(s_bl + addr) = d1[tile][jj];
      }
    }
  }

  __syncthreads();

  // ---- phase 3: GEMM2, K = 1024 over 8 waves (4 ksteps each) ----
  f32x4 acc0 = {0.f, 0.f, 0.f, 0.f}, acc1 = {0.f, 0.f, 0.f, 0.f};
  const int pl = lane & 15;
  const int arow = pl & (GP - 1);          // clamp A row: only GP point-rows exist
  const int g4 = lane >> 4;
  const int a = g4 >> 1;
  const unsigned int c0b = (unsigned)((g4 & 1) * 32);
#pragma unroll
  for (int ss = 0; ss < 4; ++ss) {
    const int s = wv * 4 + ss;
    const unsigned int byte_r = (unsigned)(arow * ROWB + s * 128 +
                                ((a ^ ((s >> 1) & 1)) << 6)) + c0b;
    const f32x4 lo = *(const f32x4*)(s_bl + byte_r);
    const f32x4 hi = *(const f32x4*)(s_bl + byte_r + 16);
    union { unsigned int u[4]; short8 v; } af;
    af.u[0] = pk2(lo.x, lo.y);
    af.u[1] = pk2(lo.z, lo.w);
    af.u[2] = pk2(hi.x, hi.y);
    af.u[3] = pk2(hi.z, hi.w);
    const short8 b0 = *(const short8*)(wf + ((unsigned)((s * 4 + g4) * 32) + pl) * 8);
    const short8 b1 = *(const short8*)(wf + ((unsigned)((s * 4 + g4) * 32) + 16 + pl) * 8);
    acc0 = __builtin_amdgcn_mfma_f32_16x16x32_bf16(af.v, b0, acc0, 0, 0, 0);
    acc1 = __builtin_amdgcn_mfma_f32_16x16x32_bf16(af.v, b1, acc1, 0, 0, 0);
  }
#pragma unroll
  for (int j = 0; j < 4; ++j) {
    const int row = g4 * 4 + j;
    if (row < GP) {
      atomicAdd(&s_cacc[row][pl], acc0[j]);
      atomicAdd(&s_cacc[row][pl + 16], acc1[j]);
    }
  }

  __syncthreads();

  if (tid < GP * COUT) {
    const int p = tid >> 5;
    const int d = tid & 31;
    const float den = s_den[p];
    float v = ((float*)s_cacc)[tid] / (den > 0.0f ? den : 1.0f) + bias[d];
    out[blockIdx.x * (GP * COUT) + tid] = fmaxf(v, 0.0f);
  }
}

extern "C" void kernel_launch(void* const* d_in, const int* in_sizes, int n_in,
                              void* d_out, int out_size, void* d_ws, size_t ws_size,
                              hipStream_t stream) {
  const float* feats        = (const float*)d_in[0];
  const float* inp_points   = (const float*)d_in[1];
  const float* out_points   = (const float*)d_in[2];
  const float* out_extents  = (const float*)d_in[3];
  const float* scale_compat = (const float*)d_in[4];
  const int*   nidx         = (const int*)d_in[5];
  const float* ndist        = (const float*)d_in[7];
  const float* kern         = (const float*)d_in[8];
  const float* bias         = (const float*)d_in[9];
  unsigned short* wf = (unsigned short*)d_ws;

  prep_w_kernel<<<(NTAP * CIN * COUT + 255) / 256, 256, 0, stream>>>(kern, wf);
  cconv_kernel<<<NOUT / GP, 512, 0, stream>>>(feats, inp_points, out_points,
                                              out_extents, scale_compat, nidx,
                                              ndist, wf, bias, (float*)d_out);
}